// Round 1
// baseline (3873.550 us; speedup 1.0000x reference)
//
#include <hip/hip_runtime.h>
#include <hip/hip_fp16.h>
#include <cstdint>
#include <cstddef>

// Problem constants
#define B_   64
#define S_   512
#define F_   512
#define H_   1024
#define KTOT 1536          // H + F augmented K
#define EPS_ 1e-3f
#define NBLK 256
#define BLK_PER_GROUP 64   // blocks sharing one batch-row group

typedef _Float16 f16x8 __attribute__((ext_vector_type(8)));
typedef float    f32x4 __attribute__((ext_vector_type(4)));

// workspace layout (bytes)
#define WS_CNT_OFF   0                      // 4 groups * 512 steps * 4B = 8 KB
#define WS_HBUF_OFF  8192                   // 2 * 64 * 1024 * 2B = 256 KB
#define WS_WT_OFF    (512*1024)             // 3*1024*1536*2B = 9 MB
#define LDS_W_BYTES  (48*KTOT*2)            // 147456
#define LDS_BYTES    (LDS_W_BYTES + 4*3*256*4)  // + reduce buf = 159744

// ---------------- weight prep: fp16, transposed, [3*H][KTOT] ----------------
// Wt[(g*H + j)][k] = (k < H) ? W_g[k][j] : U_g[k-H][j]
__global__ void prep_weights(const float* __restrict__ Wr, const float* __restrict__ Wc,
                             const float* __restrict__ Wo, const float* __restrict__ Ur,
                             const float* __restrict__ Uc, const float* __restrict__ Uo,
                             _Float16* __restrict__ Wt) {
    int b  = blockIdx.x;            // 0..191
    int g  = b >> 6;                // gate 0..2
    int j0 = (b & 63) << 4;         // 16 columns per block
    const float* W = (g == 0) ? Wr : (g == 1) ? Wc : Wo;
    const float* U = (g == 0) ? Ur : (g == 1) ? Uc : Uo;
    int jj = threadIdx.x & 15;
    int kk = threadIdx.x >> 4;      // 0..15
    for (int k0 = 0; k0 < KTOT; k0 += 16) {
        int k = k0 + kk;
        float v = (k < H_) ? W[(size_t)k * H_ + j0 + jj]
                           : U[(size_t)(k - H_) * H_ + j0 + jj];
        Wt[(size_t)(g * H_ + j0 + jj) * KTOT + k] = (_Float16)v;
    }
}

// ---------------- persistent recurrence kernel ----------------
// grid = 256 blocks (all co-resident, 1/CU), 256 threads (4 waves)
// block: batch-row group (bid>>6)*16 rows x 16 h-cols (bid&63), 3 gates
__launch_bounds__(256, 1)
__global__ void plstm_persistent(const float* __restrict__ x,
                                 const float* __restrict__ ts,
                                 const float* __restrict__ br,
                                 const float* __restrict__ bc,
                                 const float* __restrict__ bo,
                                 const _Float16* __restrict__ Wt,
                                 _Float16* __restrict__ hbuf,   // [2][64][1024] fp16
                                 unsigned* __restrict__ cnt,    // [4][512]
                                 float* __restrict__ out) {
    extern __shared__ char lds[];
    float* red = (float*)(lds + LDS_W_BYTES);   // [4 waves][3 gates][256] f32

    const int tid   = threadIdx.x;
    const int bid   = blockIdx.x;
    const int group = bid >> 6;          // batch-row group 0..3
    const int cg    = bid & 63;          // h-col group 0..63
    const int r0    = group << 4;        // batch row base
    const int c0    = cg << 4;           // h col base

    // ---- stage this block's weight slice into LDS (swizzled) ----
    // slice rows lr = g*16+j (48 rows) x KTOT, 16B chunks; swizzle byte ^ ((j&7)<<4)
    for (int m = tid; m < 48 * (KTOT / 8); m += 256) {
        int lr = m / (KTOT / 8);         // 0..47
        int kc = m % (KTOT / 8);         // 16B chunk index along k
        int j  = lr & 15;
        int g  = lr >> 4;
        f16x8 v = *(const f16x8*)(Wt + (size_t)(g * H_ + c0 + j) * KTOT + kc * 8);
        int dst = (lr * (KTOT * 2) + kc * 16) ^ ((j & 7) << 4);
        *(f16x8*)(lds + dst) = v;
    }
    __syncthreads();

    // MFMA roles (K split across 4 waves)
    const int lane = tid & 63;
    const int w    = tid >> 6;           // wave id
    const int arow = r0 + (lane & 15);   // A-fragment batch row
    const int kblk = lane >> 4;          // 0..3
    const int jcol = lane & 15;          // B-fragment column

    // elementwise ownership: thread <-> (row, col)
    const int erow = tid >> 4;
    const int ecol = tid & 15;
    const int gb   = r0 + erow;          // global batch row
    const int gh   = c0 + ecol;          // global h col
    const float biasr = br[gh], biasc = bc[gh], biaso = bo[gh];
    float cst = 0.f, kst = 0.f;

    const size_t BSH = (size_t)B_ * S_ * H_;
    unsigned* const mycnt = cnt + group * S_;

    for (int t = 0; t < S_; ++t) {
        const _Float16* hb = hbuf + (size_t)(t & 1) * B_ * H_;
        const float* xrow  = x + ((size_t)arow * S_ + t) * F_;

        // ---- phase 1: issue all 12 A-fragment loads ----
        f16x8 afr[12];
        #pragma unroll
        for (int kb = 0; kb < 12; ++kb) {
            const int base = w * 384 + kb * 32;
            if (base < H_) {
                // coherent (LLC-bypass) read of h written by other blocks/XCDs
                const _Float16* ap = hb + (size_t)arow * H_ + base + kblk * 8;
                asm volatile("global_load_dwordx4 %0, %1, off sc0 sc1"
                             : "=v"(afr[kb]) : "v"(ap));
            } else {
                const float* xp = xrow + (base - H_) + kblk * 8;
                float4 x0 = *(const float4*)xp;
                float4 x1 = *(const float4*)(xp + 4);
                f16x8 a;
                a[0] = (_Float16)x0.x; a[1] = (_Float16)x0.y;
                a[2] = (_Float16)x0.z; a[3] = (_Float16)x0.w;
                a[4] = (_Float16)x1.x; a[5] = (_Float16)x1.y;
                a[6] = (_Float16)x1.z; a[7] = (_Float16)x1.w;
                afr[kb] = a;
            }
        }
        asm volatile("s_waitcnt vmcnt(0)" ::: "memory");
        __builtin_amdgcn_sched_barrier(0);   // keep MFMAs below the waitcnt

        // ---- phase 2: LDS B-fragments + MFMA (K-split partial sums) ----
        f32x4 acc0 = {0.f,0.f,0.f,0.f}, acc1 = {0.f,0.f,0.f,0.f}, acc2 = {0.f,0.f,0.f,0.f};
        #pragma unroll
        for (int kb = 0; kb < 12; ++kb) {
            const int kw = w * 384 + kb * 32 + kblk * 8;
            const int sw = (jcol & 7) << 4;
            f16x8 b0 = *(const f16x8*)(lds + ((((0 * 16 + jcol) * KTOT + kw) * 2) ^ sw));
            f16x8 b1 = *(const f16x8*)(lds + ((((1 * 16 + jcol) * KTOT + kw) * 2) ^ sw));
            f16x8 b2 = *(const f16x8*)(lds + ((((2 * 16 + jcol) * KTOT + kw) * 2) ^ sw));
            acc0 = __builtin_amdgcn_mfma_f32_16x16x32_f16(afr[kb], b0, acc0, 0, 0, 0);
            acc1 = __builtin_amdgcn_mfma_f32_16x16x32_f16(afr[kb], b1, acc1, 0, 0, 0);
            acc2 = __builtin_amdgcn_mfma_f32_16x16x32_f16(afr[kb], b2, acc2, 0, 0, 0);
        }

        // ---- phase 3: cross-wave reduction (C layout: col=lane&15, row=(lane>>4)*4+i) ----
        {
            float* rw = red + w * 3 * 256;
            #pragma unroll
            for (int i = 0; i < 4; ++i) {
                int rr = ((lane >> 4) * 4 + i) * 16 + (lane & 15);
                rw[0 * 256 + rr] = acc0[i];
                rw[1 * 256 + rr] = acc1[i];
                rw[2 * 256 + rr] = acc2[i];
            }
        }
        __syncthreads();

        float pr = biasr, pc = biasc, po = biaso;
        #pragma unroll
        for (int ww = 0; ww < 4; ++ww) {
            pr += red[(ww * 3 + 0) * 256 + tid];
            pc += red[(ww * 3 + 1) * 256 + tid];
            po += red[(ww * 3 + 2) * 256 + tid];
        }

        // ---- phase 4: elementwise pLSTM update (f32, matches reference) ----
        const float tv = ts[(size_t)gb * S_ + t];
        const float r  = 1.f / (1.f + expf(-pr));
        kst = r * tv + (1.f - r) * kst;
        const float ctil = tanhf(pc);
        const float d = tv - kst;
        const float f = sqrtf((d + EPS_) / (d + 1.f));   // ((d+1)/(d+eps))^-0.5
        cst = f * cst + (1.f - f) * ctil;
        const float o = 1.f / (1.f + expf(-po));
        const float h = o * tanhf(cst);

        out[((size_t)gb * S_ + t) * H_ + gh] = h;
        // coherent fp16 h store for next step (agent-scope atomic -> write-through)
        {
            union { _Float16 f; unsigned short u; } cvt; cvt.f = (_Float16)h;
            unsigned short* hp = (unsigned short*)(hbuf + (size_t)((t + 1) & 1) * B_ * H_
                                                        + (size_t)gb * H_ + gh);
            __hip_atomic_store(hp, cvt.u, __ATOMIC_RELAXED, __HIP_MEMORY_SCOPE_AGENT);
        }

        if (t == S_ - 1) {
            out[BSH +                 (size_t)gb * H_ + gh] = h;    // h_T
            out[BSH + 1 * B_ * H_ +   (size_t)gb * H_ + gh] = cst;  // c_T
            out[BSH + 2 * B_ * H_ +   (size_t)gb * H_ + gh] = kst;  // k_T
        } else {
            // ---- per-group barrier: 64 blocks ----
            __syncthreads();   // drains vmcnt -> all h stores globally visible
            if (tid == 0) {
                unsigned* pcnt = mycnt + t;
                __hip_atomic_fetch_add(pcnt, 1u, __ATOMIC_RELAXED, __HIP_MEMORY_SCOPE_AGENT);
                unsigned spin = 0;
                while (__hip_atomic_load(pcnt, __ATOMIC_RELAXED,
                                         __HIP_MEMORY_SCOPE_AGENT) < BLK_PER_GROUP) {
                    __builtin_amdgcn_s_sleep(1);
                    if (++spin > (1u << 13)) break;   // anti-hang safety valve
                }
            }
            __syncthreads();
            asm volatile("" ::: "memory");
        }
    }
}

extern "C" void kernel_launch(void* const* d_in, const int* in_sizes, int n_in,
                              void* d_out, int out_size, void* d_ws, size_t ws_size,
                              hipStream_t stream) {
    (void)in_sizes; (void)n_in; (void)out_size; (void)ws_size;
    const float* x  = (const float*)d_in[0];
    const float* ts = (const float*)d_in[1];
    const float* Ur = (const float*)d_in[2];
    const float* Wr = (const float*)d_in[3];
    const float* br = (const float*)d_in[4];
    const float* Uc = (const float*)d_in[5];
    const float* Wc = (const float*)d_in[6];
    const float* bc = (const float*)d_in[7];
    const float* Uo = (const float*)d_in[8];
    const float* Wo = (const float*)d_in[9];
    const float* bo = (const float*)d_in[10];
    float* out = (float*)d_out;

    char* ws = (char*)d_ws;
    unsigned*  cnt  = (unsigned*)(ws + WS_CNT_OFF);
    _Float16*  hbuf = (_Float16*)(ws + WS_HBUF_OFF);
    _Float16*  Wt   = (_Float16*)(ws + WS_WT_OFF);

    // zero barrier counters + h double-buffer (h_0 = 0); re-done every launch
    hipMemsetAsync(ws, 0, WS_HBUF_OFF + 2 * B_ * H_ * 2, stream);

    prep_weights<<<192, 256, 0, stream>>>(Wr, Wc, Wo, Ur, Uc, Uo, Wt);

    hipFuncSetAttribute((const void*)plstm_persistent,
                        hipFuncAttributeMaxDynamicSharedMemorySize, LDS_BYTES);
    plstm_persistent<<<NBLK, 256, LDS_BYTES, stream>>>(x, ts, br, bc, bo, Wt, hbuf, cnt, out);
}

// Round 2
// 3376.896 us; speedup vs baseline: 1.1471x; 1.1471x over previous
//
#include <hip/hip_runtime.h>
#include <hip/hip_fp16.h>
#include <cstdint>
#include <cstddef>

// Problem constants
#define B_   64
#define S_   512
#define F_   512
#define H_   1024
#define KTOT 1536          // H + F augmented K
#define EPS_ 1e-3f
#define NBLK 256

typedef _Float16 f16x8 __attribute__((ext_vector_type(8)));
typedef float    f32x4 __attribute__((ext_vector_type(4)));

// workspace layout (bytes)
#define WS_FLAG_OFF  0                      // [4 groups][64 producers] u32 = 1 KB
#define WS_HBUF_OFF  4096                   // [3][64][1024] fp16 = 384 KB
#define WS_WT_OFF    409600                 // [3*1024][1536] fp16 = 9 MB  (total ~9.4 MB)

// ---------------- weight prep: fp16, transposed, [3*H][KTOT] ----------------
// Wt[(g*H + j)][k] = (k < H) ? W_g[k][j] : U_g[k-H][j]
__global__ void prep_weights(const float* __restrict__ Wr, const float* __restrict__ Wc,
                             const float* __restrict__ Wo, const float* __restrict__ Ur,
                             const float* __restrict__ Uc, const float* __restrict__ Uo,
                             _Float16* __restrict__ Wt) {
    int b  = blockIdx.x;            // 0..191
    int g  = b >> 6;                // gate 0..2
    int j0 = (b & 63) << 4;         // 16 columns per block
    const float* W = (g == 0) ? Wr : (g == 1) ? Wc : Wo;
    const float* U = (g == 0) ? Ur : (g == 1) ? Uc : Uo;
    int jj = threadIdx.x & 15;
    int kk = threadIdx.x >> 4;      // 0..15
    for (int k0 = 0; k0 < KTOT; k0 += 16) {
        int k = k0 + kk;
        float v = (k < H_) ? W[(size_t)k * H_ + j0 + jj]
                           : U[(size_t)(k - H_) * H_ + j0 + jj];
        Wt[(size_t)(g * H_ + j0 + jj) * KTOT + k] = (_Float16)v;
    }
}

// ---------------- persistent recurrence kernel ----------------
// grid = 256 blocks (co-resident), 256 threads (4 waves, 1/SIMD -> 512 VGPR budget)
// block: batch-row group (bid>>6)*16 rows x 16 h-cols (bid&63) x 3 gates
// weights live entirely in registers (36 f16x8 B-fragments per thread).
__launch_bounds__(256, 1)
__global__ void plstm_persistent(const float* __restrict__ x,
                                 const float* __restrict__ ts,
                                 const float* __restrict__ br,
                                 const float* __restrict__ bc,
                                 const float* __restrict__ bo,
                                 const _Float16* __restrict__ Wt,
                                 _Float16* __restrict__ hbuf,   // [3][64][1024] fp16
                                 unsigned* __restrict__ flags,  // [4][64] monotone step tags
                                 float* __restrict__ out) {
    __shared__ float    red[4 * 3 * 256];   // 12 KB cross-wave reduce
    __shared__ _Float16 hpack[16][16];      // packed h tile for wave-0 store

    const int tid   = threadIdx.x;
    const int bid   = blockIdx.x;
    const int group = bid >> 6;          // batch-row group 0..3
    const int cg    = bid & 63;          // h-col group 0..63
    const int r0    = group << 4;
    const int c0    = cg << 4;

    const int lane = tid & 63;
    const int w    = tid >> 6;           // wave id: k-range owner
    const int arow = r0 + (lane & 15);   // A-fragment batch row
    const int kblk = lane >> 4;          // 0..3 (8 k-elems each)
    const int jcol = lane & 15;          // B-fragment column

    const int erow = tid >> 4;           // elementwise ownership
    const int ecol = tid & 15;
    const int gb   = r0 + erow;
    const int gh   = c0 + ecol;
    const float biasr = br[gh], biasc = bc[gh], biaso = bo[gh];
    float cst = 0.f, kst = 0.f, hval = 0.f;

    // ---- load this thread's 36 B-fragments into registers (once) ----
    // wave w owns k in [256w,256w+256) (h part) and [1024+128w, 1024+128w+128) (x part)
    f16x8 bf[3][12];
    #pragma unroll
    for (int g = 0; g < 3; ++g)
        #pragma unroll
        for (int sub = 0; sub < 12; ++sub) {
            const int kb = (sub < 8) ? (w * 256 + sub * 32)
                                     : (H_ + w * 128 + (sub - 8) * 32);
            bf[g][sub] = *(const f16x8*)(Wt + (size_t)(g * H_ + c0 + jcol) * KTOT
                                            + kb + kblk * 8);
        }

    unsigned* const grpflags = flags + group * 64;
    const unsigned* const myfl = grpflags + w * 16 + (lane & 15); // this wave's 16 producers
    unsigned* const myflag = grpflags + cg;

    // x prefetch double-buffer (f32 regs, cvt to fp16 at use)
    f32x4 xnA[8], xnB[8];
    #pragma unroll
    for (int i = 0; i < 4; ++i) {
        const float* xp = x + (size_t)arow * S_ * F_ + w * 128 + i * 32 + kblk * 8;
        xnA[2 * i]     = *(const f32x4*)xp;
        xnA[2 * i + 1] = *(const f32x4*)(xp + 4);
    }

    auto step = [&](int t, f32x4* xc, f32x4* xn) {
        // ---- wait for this wave's k-quarter producers (monotone flags) ----
        if (t > 0) {
            for (unsigned it = 0; it < (1u << 14); ++it) {
                unsigned v;
                asm volatile("global_load_dword %0, %1, off sc0 sc1\n\t"
                             "s_waitcnt vmcnt(0)"
                             : "=v"(v) : "v"(myfl) : "memory");
                if (__all((int)(v >= (unsigned)t))) break;
            }
        }
        const float tv = ts[(size_t)gb * S_ + t];   // issue early, used late

        // ---- h A-fragments (coherent LLC reads) ----
        const _Float16* hb = hbuf + (size_t)(t % 3) * B_ * H_;
        f16x8 hfr[8];
        #pragma unroll
        for (int sub = 0; sub < 8; ++sub) {
            const _Float16* hp = hb + (size_t)arow * H_ + w * 256 + sub * 32 + kblk * 8;
            asm volatile("global_load_dwordx4 %0, %1, off sc0 sc1"
                         : "=v"(hfr[sub]) : "v"(hp));
        }
        asm volatile("s_waitcnt vmcnt(0)" ::: "memory");
        __builtin_amdgcn_sched_barrier(0);

        // ---- MFMA: 3 gates x (8 h-subk + 4 x-subk) ----
        f32x4 acc0 = {0,0,0,0}, acc1 = {0,0,0,0}, acc2 = {0,0,0,0};
        #pragma unroll
        for (int sub = 0; sub < 8; ++sub) {
            acc0 = __builtin_amdgcn_mfma_f32_16x16x32_f16(hfr[sub], bf[0][sub], acc0, 0, 0, 0);
            acc1 = __builtin_amdgcn_mfma_f32_16x16x32_f16(hfr[sub], bf[1][sub], acc1, 0, 0, 0);
            acc2 = __builtin_amdgcn_mfma_f32_16x16x32_f16(hfr[sub], bf[2][sub], acc2, 0, 0, 0);
        }
        #pragma unroll
        for (int i = 0; i < 4; ++i) {
            f16x8 a;
            #pragma unroll
            for (int r = 0; r < 4; ++r) {
                a[r]     = (_Float16)xc[2 * i][r];
                a[4 + r] = (_Float16)xc[2 * i + 1][r];
            }
            acc0 = __builtin_amdgcn_mfma_f32_16x16x32_f16(a, bf[0][8 + i], acc0, 0, 0, 0);
            acc1 = __builtin_amdgcn_mfma_f32_16x16x32_f16(a, bf[1][8 + i], acc1, 0, 0, 0);
            acc2 = __builtin_amdgcn_mfma_f32_16x16x32_f16(a, bf[2][8 + i], acc2, 0, 0, 0);
        }

        // ---- prefetch x for t+1 (off critical path) ----
        if (t + 1 < S_) {
            #pragma unroll
            for (int i = 0; i < 4; ++i) {
                const float* xp = x + ((size_t)arow * S_ + (t + 1)) * F_
                                    + w * 128 + i * 32 + kblk * 8;
                xn[2 * i]     = *(const f32x4*)xp;
                xn[2 * i + 1] = *(const f32x4*)(xp + 4);
            }
        }

        // ---- cross-wave reduce (C layout: col=lane&15, row=(lane>>4)*4+i) ----
        {
            float* rw = red + w * 768;
            #pragma unroll
            for (int i = 0; i < 4; ++i) {
                const int rr = ((lane >> 4) * 4 + i) * 16 + (lane & 15);
                rw[rr]       = acc0[i];
                rw[256 + rr] = acc1[i];
                rw[512 + rr] = acc2[i];
            }
        }
        __syncthreads();
        float pr = biasr, pc = biasc, po = biaso;
        #pragma unroll
        for (int ww = 0; ww < 4; ++ww) {
            pr += red[ww * 768 + tid];
            pc += red[ww * 768 + 256 + tid];
            po += red[ww * 768 + 512 + tid];
        }

        // ---- elementwise pLSTM update (f32) ----
        const float r = 1.f / (1.f + __expf(-pr));
        kst = r * tv + (1.f - r) * kst;
        const float e2 = __expf(2.f * pc);
        const float ctil = (e2 - 1.f) / (e2 + 1.f);
        const float d = tv - kst;
        const float f = __fsqrt_rn((d + EPS_) / (d + 1.f));  // ((d+1)/(d+eps))^-0.5
        cst = f * cst + (1.f - f) * ctil;
        const float o = 1.f / (1.f + __expf(-po));
        const float e2c = __expf(2.f * cst);
        hval = o * ((e2c - 1.f) / (e2c + 1.f));

        hpack[erow][ecol] = (_Float16)hval;
        if (w != 0) out[((size_t)gb * S_ + t) * H_ + gh] = hval;  // off critical path
        __syncthreads();

        // ---- wave 0: publish h_{t+1} then flag, THEN its out stores ----
        if (w == 0) {
            if (t + 1 < S_) {
                if (lane < 32) {
                    const int row = lane >> 1, half = lane & 1;
                    f16x8 v = *(const f16x8*)&hpack[row][half * 8];
                    _Float16* hp = hbuf + (size_t)((t + 1) % 3) * B_ * H_
                                        + (size_t)(r0 + row) * H_ + c0 + half * 8;
                    asm volatile("global_store_dwordx4 %0, %1, off sc0 sc1"
                                 :: "v"(hp), "v"(v) : "memory");
                }
                asm volatile("s_waitcnt vmcnt(0)" ::: "memory");
                if (lane == 0) {
                    unsigned fv = (unsigned)(t + 1);
                    asm volatile("global_store_dword %0, %1, off sc0 sc1"
                                 :: "v"(myflag), "v"(fv) : "memory");
                }
            }
            out[((size_t)gb * S_ + t) * H_ + gh] = hval;
        }
    };

    for (int t = 0; t < S_; t += 2) {
        step(t,     xnA, xnB);
        step(t + 1, xnB, xnA);
    }

    // final states
    const size_t BSH = (size_t)B_ * S_ * H_;
    out[BSH +                         (size_t)gb * H_ + gh] = hval;  // h_T
    out[BSH + (size_t)B_ * H_ +       (size_t)gb * H_ + gh] = cst;   // c_T
    out[BSH + 2 * (size_t)B_ * H_ +   (size_t)gb * H_ + gh] = kst;   // k_T
}

extern "C" void kernel_launch(void* const* d_in, const int* in_sizes, int n_in,
                              void* d_out, int out_size, void* d_ws, size_t ws_size,
                              hipStream_t stream) {
    (void)in_sizes; (void)n_in; (void)out_size; (void)ws_size;
    const float* x  = (const float*)d_in[0];
    const float* ts = (const float*)d_in[1];
    const float* Ur = (const float*)d_in[2];
    const float* Wr = (const float*)d_in[3];
    const float* br = (const float*)d_in[4];
    const float* Uc = (const float*)d_in[5];
    const float* Wc = (const float*)d_in[6];
    const float* bc = (const float*)d_in[7];
    const float* Uo = (const float*)d_in[8];
    const float* Wo = (const float*)d_in[9];
    const float* bo = (const float*)d_in[10];
    float* out = (float*)d_out;

    char* ws = (char*)d_ws;
    unsigned*  flags = (unsigned*)(ws + WS_FLAG_OFF);
    _Float16*  hbuf  = (_Float16*)(ws + WS_HBUF_OFF);
    _Float16*  Wt    = (_Float16*)(ws + WS_WT_OFF);

    // zero flags + h buffer 0 (h_0 = 0); re-done every launch (graph-replay safe)
    hipMemsetAsync(ws, 0, WS_HBUF_OFF + B_ * H_ * 2, stream);

    prep_weights<<<192, 256, 0, stream>>>(Wr, Wc, Wo, Ur, Uc, Uo, Wt);

    plstm_persistent<<<NBLK, 256, 0, stream>>>(x, ts, br, bc, bo, Wt, hbuf, flags, out);
}